// Round 7
// baseline (440.945 us; speedup 1.0000x reference)
//
#include <hip/hip_runtime.h>
#include <cstdint>
#include <cstddef>

#define N_NODES 100000
#define N_EDGES 1600000
#define F_IN 256
#define F_HID 128
#define F_OUT 40
#define F_OUT_P 64   // h2 padded cols (bf16)

#define BKT_SHIFT 8
#define BKT_SIZE 256
#define NBKT ((N_NODES + BKT_SIZE - 1) / BKT_SIZE)   // 391
#define P1_EPT 4
#define P1_EPB (256 * P1_EPT)                        // 1024 edges/block
#define P1_NBLK ((N_EDGES + P1_EPB - 1) / P1_EPB)    // 1563

typedef __attribute__((ext_vector_type(8))) short short8;
typedef __attribute__((ext_vector_type(4))) float floatx4;
typedef __attribute__((ext_vector_type(2))) float floatx2;

__device__ __forceinline__ float bf2f(unsigned short u) {
    return __uint_as_float(((unsigned int)u) << 16);
}
__device__ __forceinline__ unsigned short f2bf(float f) {
    unsigned int x = __float_as_uint(f);
    x += 0x7fffu + ((x >> 16) & 1u);   // RNE
    return (unsigned short)(x >> 16);
}
__device__ __forceinline__ float lo16(unsigned int u) { return __uint_as_float(u << 16); }
__device__ __forceinline__ float hi16(unsigned int u) { return __uint_as_float(u & 0xFFFF0000u); }
__device__ __forceinline__ unsigned char f2fp8(float v) {
    return (unsigned char)(__builtin_amdgcn_cvt_pk_fp8_f32(v, v, 0, false) & 0xFF);
}

// ---------------- P1a: bucket histogram ----------------
__global__ __launch_bounds__(256) void k_hist(const int* __restrict__ dst,
                                              int* __restrict__ gtot) {
    __shared__ int hist[NBKT];
    for (int i = threadIdx.x; i < NBKT; i += 256) hist[i] = 0;
    __syncthreads();
    int base = blockIdx.x * P1_EPB;
    #pragma unroll
    for (int i = 0; i < P1_EPT; ++i) {
        int e = base + threadIdx.x + i * 256;
        if (e < N_EDGES) atomicAdd(&hist[dst[e] >> BKT_SHIFT], 1);
    }
    __syncthreads();
    for (int i = threadIdx.x; i < NBKT; i += 256)
        if (hist[i]) atomicAdd(&gtot[i], hist[i]);
}

// ---------------- P1b: scan bucket totals ----------------
__global__ __launch_bounds__(256) void k_bktscan(const int* __restrict__ gtot,
                                                 int* __restrict__ boff,
                                                 int* __restrict__ bcur) {
    __shared__ int lds[NBKT + 1];
    int t = threadIdx.x;
    for (int i = t; i < NBKT; i += 256) lds[i] = gtot[i];
    __syncthreads();
    if (t == 0) {
        int run = 0;
        for (int i = 0; i < NBKT; ++i) { int v = lds[i]; lds[i] = run; run += v; }
        lds[NBKT] = run;
    }
    __syncthreads();
    for (int i = t; i <= NBKT; i += 256) {
        boff[i] = lds[i];
        if (i < NBKT) bcur[i] = lds[i];
    }
}

// ---------------- P1c: bin edges by bucket (4B packed records) ----------------
__global__ __launch_bounds__(256) void k_bin(const int* __restrict__ src,
                                             const int* __restrict__ dst,
                                             int* __restrict__ bcur,
                                             unsigned int* __restrict__ binned) {
    __shared__ int hist[NBKT];
    __shared__ int baseg[NBKT];
    __shared__ int cnt2[NBKT];
    for (int i = threadIdx.x; i < NBKT; i += 256) { hist[i] = 0; cnt2[i] = 0; }
    __syncthreads();
    int base = blockIdx.x * P1_EPB;
    int s[P1_EPT], d[P1_EPT];
    #pragma unroll
    for (int i = 0; i < P1_EPT; ++i) {
        int e = base + threadIdx.x + i * 256;
        if (e < N_EDGES) {
            s[i] = src[e]; d[i] = dst[e];
            atomicAdd(&hist[d[i] >> BKT_SHIFT], 1);
        } else d[i] = -1;
    }
    __syncthreads();
    for (int i = threadIdx.x; i < NBKT; i += 256)
        baseg[i] = hist[i] ? atomicAdd(&bcur[i], hist[i]) : 0;
    __syncthreads();
    #pragma unroll
    for (int i = 0; i < P1_EPT; ++i) {
        if (d[i] >= 0) {
            int b = d[i] >> BKT_SHIFT;
            int r = atomicAdd(&cnt2[b], 1);
            binned[baseg[b] + r] =
                (unsigned int)s[i] | ((unsigned int)(d[i] & (BKT_SIZE - 1)) << 17);
        }
    }
}

// ---------------- P2: per-bucket place -> CSR, off[], dinv[] (no global atomics) ----------------
__global__ __launch_bounds__(256) void k_place(const unsigned int* __restrict__ binned,
                                               const int* __restrict__ boff,
                                               int* __restrict__ off,
                                               float* __restrict__ dinv,
                                               int* __restrict__ ssrc) {
    __shared__ int cnt[BKT_SIZE];
    __shared__ int ioff[BKT_SIZE];
    __shared__ int sexcl[BKT_SIZE];
    int b = blockIdx.x, t = threadIdx.x;
    int e0 = boff[b], e1 = boff[b + 1];
    cnt[t] = 0;
    __syncthreads();
    for (int i = e0 + t; i < e1; i += 256)
        atomicAdd(&cnt[binned[i] >> 17], 1);
    __syncthreads();
    int v = cnt[t];
    ioff[t] = v;
    __syncthreads();
    for (int ofs = 1; ofs < 256; ofs <<= 1) {
        int y = (t >= ofs) ? ioff[t - ofs] : 0;
        __syncthreads();
        ioff[t] += y;
        __syncthreads();
    }
    int excl = ioff[t] - v;   // exclusive prefix within bucket
    int n = b * BKT_SIZE + t;
    if (n < N_NODES) {
        off[n] = e0 + excl;
        dinv[n] = rsqrtf((float)v + 1.0f);
    }
    if (b == NBKT - 1 && t == 0) off[N_NODES] = N_EDGES;
    __syncthreads();
    cnt[t] = 0;
    sexcl[t] = excl;
    __syncthreads();
    for (int i = e0 + t; i < e1; i += 256) {
        unsigned int rec = binned[i];
        int dl = rec >> 17;
        int r = atomicAdd(&cnt[dl], 1);
        ssrc[e0 + sexcl[dl] + r] = (int)(rec & 0x1FFFFu);
    }
}

// ---------------- P3: build (src, dinv[src]) records ----------------
__global__ __launch_bounds__(256) void k_mkrec(const int* __restrict__ ssrc,
                                               const float* __restrict__ dinv,
                                               int2* __restrict__ edges) {
    int i = blockIdx.x * blockDim.x + threadIdx.x;   // groups of 4
    if (i < N_EDGES / 4) {
        int4 s4 = ((const int4*)ssrc)[i];
        int4* ep = (int4*)(edges + (size_t)i * 4);
        ep[0] = make_int4(s4.x, __float_as_int(dinv[s4.x]),
                          s4.y, __float_as_int(dinv[s4.y]));
        ep[1] = make_int4(s4.z, __float_as_int(dinv[s4.z]),
                          s4.w, __float_as_int(dinv[s4.w]));
    }
}

// ---------------- weight conversion (merged) ----------------
__global__ void k_convW(const float* __restrict__ W1, const float* __restrict__ W2,
                        unsigned short* __restrict__ W1t, unsigned short* __restrict__ W2t) {
    int i = blockIdx.x * blockDim.x + threadIdx.x;
    if (i < F_IN * F_HID) {
        int k = i >> 7, n = i & 127;
        W1t[n * F_IN + k] = f2bf(W1[i]);
    } else {
        int j = i - F_IN * F_HID;
        if (j < F_OUT_P * F_HID) {
            int k = j >> 6, n = j & 63;
            float v = (n < F_OUT) ? W2[k * F_OUT + n] : 0.0f;
            W2t[n * F_HID + k] = f2bf(v);
        }
    }
}

// ---------------- GEMM1 (MFMA bf16): x[N,256]f32 @ W1 -> h[N,128] fp8-e4m3 ----------------
__global__ __launch_bounds__(256) void k_gemm1(const float* __restrict__ A,
                                               const unsigned short* __restrict__ Wt,
                                               unsigned char* __restrict__ C) {
    __shared__ unsigned short As[128][40];
    __shared__ unsigned short Ws[128][40];
    int t = threadIdx.x;
    int wave = t >> 6, lane = t & 63;
    int quad = lane >> 4, l16 = lane & 15;
    int row0 = blockIdx.x * 128;
    floatx4 acc[2][8];
    #pragma unroll
    for (int i = 0; i < 2; ++i)
        #pragma unroll
        for (int j = 0; j < 8; ++j)
            #pragma unroll
            for (int r = 0; r < 4; ++r) acc[i][j][r] = 0.0f;

    for (int k0 = 0; k0 < F_IN; k0 += 32) {
        #pragma unroll
        for (int i = 0; i < 4; ++i) {
            int idx = t + i * 256;
            int r = idx >> 3, c = idx & 7;
            int gr = row0 + r; if (gr > N_NODES - 1) gr = N_NODES - 1;
            float4 va = *(const float4*)(A + (size_t)gr * F_IN + k0 + c * 4);
            ushort4 u;
            u.x = f2bf(va.x); u.y = f2bf(va.y); u.z = f2bf(va.z); u.w = f2bf(va.w);
            *(ushort4*)(&As[r][c * 4]) = u;
        }
        #pragma unroll
        for (int i = 0; i < 2; ++i) {
            int idx = t + i * 256;
            int n = idx >> 2, c = idx & 3;
            ushort4 w0 = *(const ushort4*)(Wt + (size_t)n * F_IN + k0 + c * 8);
            ushort4 w1 = *(const ushort4*)(Wt + (size_t)n * F_IN + k0 + c * 8 + 4);
            *(ushort4*)(&Ws[n][c * 8]) = w0;
            *(ushort4*)(&Ws[n][c * 8 + 4]) = w1;
        }
        __syncthreads();
        short8 af[2];
        #pragma unroll
        for (int rt = 0; rt < 2; ++rt)
            af[rt] = *(const short8*)(&As[wave * 32 + rt * 16 + l16][quad * 8]);
        #pragma unroll
        for (int ct = 0; ct < 8; ++ct) {
            short8 bf = *(const short8*)(&Ws[ct * 16 + l16][quad * 8]);
            acc[0][ct] = __builtin_amdgcn_mfma_f32_16x16x32_bf16(af[0], bf, acc[0][ct], 0, 0, 0);
            acc[1][ct] = __builtin_amdgcn_mfma_f32_16x16x32_bf16(af[1], bf, acc[1][ct], 0, 0, 0);
        }
        __syncthreads();
    }
    #pragma unroll
    for (int rt = 0; rt < 2; ++rt) {
        #pragma unroll
        for (int ct = 0; ct < 8; ++ct) {
            #pragma unroll
            for (int r = 0; r < 4; ++r) {
                int row = row0 + wave * 32 + rt * 16 + quad * 4 + r;
                if (row < N_NODES)
                    C[(size_t)row * F_HID + ct * 16 + l16] = f2fp8(acc[rt][ct][r]);
            }
        }
    }
}

// ---------------- agg1: h (fp8) gather, 4 quarter-waves x 4 edges in flight ----------------
// row = 128 fp8 bytes = 16 lanes x uint2; lane covers cols 8*l16..+7.
#define ACCF8(u2, wgt) { \
    floatx2 p0 = __builtin_amdgcn_cvt_pk_f32_fp8(u2.x, false); \
    floatx2 p1 = __builtin_amdgcn_cvt_pk_f32_fp8(u2.x, true); \
    floatx2 p2 = __builtin_amdgcn_cvt_pk_f32_fp8(u2.y, false); \
    floatx2 p3 = __builtin_amdgcn_cvt_pk_f32_fp8(u2.y, true); \
    a[0] += wgt * p0.x; a[1] += wgt * p0.y; a[2] += wgt * p1.x; a[3] += wgt * p1.y; \
    a[4] += wgt * p2.x; a[5] += wgt * p2.y; a[6] += wgt * p3.x; a[7] += wgt * p3.y; }

__global__ __launch_bounds__(256) void k_agg1(const unsigned char* __restrict__ h_,
                                              const int* __restrict__ off,
                                              const int2* __restrict__ edges,
                                              const float* __restrict__ dinv,
                                              const float* __restrict__ b1,
                                              unsigned short* __restrict__ h1_) {
    const uint2* h = (const uint2*)h_;   // row = 16 uint2 (128 fp8)
    uint4* h1 = (uint4*)h1_;
    int node = blockIdx.x * 4 + (threadIdx.x >> 6);
    int lane = threadIdx.x & 63;
    int q = lane >> 4, l16 = lane & 15;
    if (node >= N_NODES) return;
    int s0 = off[node], s1 = off[node + 1];
    int nE = s1 - s0;
    float dn = dinv[node];
    float a[8] = {};
    if (q == 0) {
        uint2 sv = h[(size_t)node * 16 + l16];
        ACCF8(sv, dn);
    }
    int end4 = s0 + (nE & ~3);
    int e = s0 + q;
    for (; e + 12 < end4; e += 16) {
        int2 r0 = edges[e], r1 = edges[e + 4], r2 = edges[e + 8], r3 = edges[e + 12];
        uint2 v0 = h[(size_t)r0.x * 16 + l16];
        uint2 v1 = h[(size_t)r1.x * 16 + l16];
        uint2 v2 = h[(size_t)r2.x * 16 + l16];
        uint2 v3 = h[(size_t)r3.x * 16 + l16];
        ACCF8(v0, __int_as_float(r0.y));
        ACCF8(v1, __int_as_float(r1.y));
        ACCF8(v2, __int_as_float(r2.y));
        ACCF8(v3, __int_as_float(r3.y));
    }
    for (; e < end4; e += 4) {
        int2 r0 = edges[e];
        uint2 v0 = h[(size_t)r0.x * 16 + l16];
        ACCF8(v0, __int_as_float(r0.y));
    }
    if (q < (nE & 3)) {
        int2 r0 = edges[end4 + q];
        uint2 v0 = h[(size_t)r0.x * 16 + l16];
        ACCF8(v0, __int_as_float(r0.y));
    }
    #pragma unroll
    for (int i = 0; i < 8; ++i) {
        a[i] += __shfl_xor(a[i], 16);
        a[i] += __shfl_xor(a[i], 32);
    }
    if (q == 0) {
        float4 bb0 = ((const float4*)b1)[l16 * 2];
        float4 bb1 = ((const float4*)b1)[l16 * 2 + 1];
        unsigned short c0 = f2bf(fmaxf(a[0] * dn + bb0.x, 0.0f));
        unsigned short c1 = f2bf(fmaxf(a[1] * dn + bb0.y, 0.0f));
        unsigned short c2 = f2bf(fmaxf(a[2] * dn + bb0.z, 0.0f));
        unsigned short c3 = f2bf(fmaxf(a[3] * dn + bb0.w, 0.0f));
        unsigned short c4 = f2bf(fmaxf(a[4] * dn + bb1.x, 0.0f));
        unsigned short c5 = f2bf(fmaxf(a[5] * dn + bb1.y, 0.0f));
        unsigned short c6 = f2bf(fmaxf(a[6] * dn + bb1.z, 0.0f));
        unsigned short c7 = f2bf(fmaxf(a[7] * dn + bb1.w, 0.0f));
        uint4 r;
        r.x = (unsigned int)c0 | ((unsigned int)c1 << 16);
        r.y = (unsigned int)c2 | ((unsigned int)c3 << 16);
        r.z = (unsigned int)c4 | ((unsigned int)c5 << 16);
        r.w = (unsigned int)c6 | ((unsigned int)c7 << 16);
        h1[(size_t)node * 16 + l16] = r;
    }
}

// ---------------- GEMM2 (MFMA bf16): h1[N,128]bf16 @ W2 -> h2[N,64]bf16 ----------------
__global__ __launch_bounds__(256) void k_gemm2(const unsigned short* __restrict__ A,
                                               const unsigned short* __restrict__ Wt,
                                               unsigned short* __restrict__ C) {
    __shared__ unsigned short As[128][136];
    __shared__ unsigned short Ws[64][136];
    int t = threadIdx.x;
    int wave = t >> 6, lane = t & 63;
    int quad = lane >> 4, l16 = lane & 15;
    int row0 = blockIdx.x * 128;
    floatx4 acc[2][4];
    #pragma unroll
    for (int i = 0; i < 2; ++i)
        #pragma unroll
        for (int j = 0; j < 4; ++j)
            #pragma unroll
            for (int r = 0; r < 4; ++r) acc[i][j][r] = 0.0f;

    #pragma unroll
    for (int i = 0; i < 8; ++i) {
        int idx = t + i * 256;
        int r = idx >> 4, c = idx & 15;
        int gr = row0 + r; if (gr > N_NODES - 1) gr = N_NODES - 1;
        ushort4 w0 = *(const ushort4*)(A + (size_t)gr * F_HID + c * 8);
        ushort4 w1 = *(const ushort4*)(A + (size_t)gr * F_HID + c * 8 + 4);
        *(ushort4*)(&As[r][c * 8]) = w0;
        *(ushort4*)(&As[r][c * 8 + 4]) = w1;
    }
    #pragma unroll
    for (int i = 0; i < 4; ++i) {
        int idx = t + i * 256;
        int n = idx >> 4, c = idx & 15;
        ushort4 w0 = *(const ushort4*)(Wt + (size_t)n * F_HID + c * 8);
        ushort4 w1 = *(const ushort4*)(Wt + (size_t)n * F_HID + c * 8 + 4);
        *(ushort4*)(&Ws[n][c * 8]) = w0;
        *(ushort4*)(&Ws[n][c * 8 + 4]) = w1;
    }
    __syncthreads();
    #pragma unroll
    for (int ks = 0; ks < 4; ++ks) {
        int k0 = ks * 32;
        short8 af[2];
        #pragma unroll
        for (int rt = 0; rt < 2; ++rt)
            af[rt] = *(const short8*)(&As[wave * 32 + rt * 16 + l16][k0 + quad * 8]);
        #pragma unroll
        for (int ct = 0; ct < 4; ++ct) {
            short8 bf = *(const short8*)(&Ws[ct * 16 + l16][k0 + quad * 8]);
            acc[0][ct] = __builtin_amdgcn_mfma_f32_16x16x32_bf16(af[0], bf, acc[0][ct], 0, 0, 0);
            acc[1][ct] = __builtin_amdgcn_mfma_f32_16x16x32_bf16(af[1], bf, acc[1][ct], 0, 0, 0);
        }
    }
    #pragma unroll
    for (int rt = 0; rt < 2; ++rt) {
        #pragma unroll
        for (int ct = 0; ct < 4; ++ct) {
            #pragma unroll
            for (int r = 0; r < 4; ++r) {
                int row = row0 + wave * 32 + rt * 16 + quad * 4 + r;
                if (row < N_NODES)
                    C[(size_t)row * F_OUT_P + ct * 16 + l16] = f2bf(acc[rt][ct][r]);
            }
        }
    }
}

// ---------------- agg2 + bias + log_softmax: 4 quarter-waves x 4 edges in flight ----------------
#define ACC4(u2, wgt) { \
    a[0] += wgt * lo16(u2.x); a[1] += wgt * hi16(u2.x); \
    a[2] += wgt * lo16(u2.y); a[3] += wgt * hi16(u2.y); }

__global__ __launch_bounds__(256) void k_agg2(const unsigned short* __restrict__ h2_,
                                              const int* __restrict__ off,
                                              const int2* __restrict__ edges,
                                              const float* __restrict__ dinv,
                                              const float* __restrict__ b2,
                                              float* __restrict__ out) {
    const uint2* h2 = (const uint2*)h2_;  // row = 16 uint2 (64 bf16)
    int node = blockIdx.x * 4 + (threadIdx.x >> 6);
    int lane = threadIdx.x & 63;
    int q = lane >> 4, l16 = lane & 15;
    if (node >= N_NODES) return;
    int s0 = off[node], s1 = off[node + 1];
    int nE = s1 - s0;
    float dn = dinv[node];
    float a[4] = {};
    if (q == 0) {
        uint2 sv = h2[(size_t)node * 16 + l16];
        ACC4(sv, dn);
    }
    int end4 = s0 + (nE & ~3);
    int e = s0 + q;
    for (; e + 12 < end4; e += 16) {
        int2 r0 = edges[e], r1 = edges[e + 4], r2 = edges[e + 8], r3 = edges[e + 12];
        uint2 v0 = h2[(size_t)r0.x * 16 + l16];
        uint2 v1 = h2[(size_t)r1.x * 16 + l16];
        uint2 v2 = h2[(size_t)r2.x * 16 + l16];
        uint2 v3 = h2[(size_t)r3.x * 16 + l16];
        ACC4(v0, __int_as_float(r0.y));
        ACC4(v1, __int_as_float(r1.y));
        ACC4(v2, __int_as_float(r2.y));
        ACC4(v3, __int_as_float(r3.y));
    }
    for (; e < end4; e += 4) {
        int2 r0 = edges[e];
        uint2 v0 = h2[(size_t)r0.x * 16 + l16];
        ACC4(v0, __int_as_float(r0.y));
    }
    if (q < (nE & 3)) {
        int2 r0 = edges[end4 + q];
        uint2 v0 = h2[(size_t)r0.x * 16 + l16];
        ACC4(v0, __int_as_float(r0.y));
    }
    #pragma unroll
    for (int i = 0; i < 4; ++i) {
        a[i] += __shfl_xor(a[i], 16);
        a[i] += __shfl_xor(a[i], 32);
    }
    int c0 = l16 * 4;
    float v0 = (c0 < F_OUT)     ? (a[0] * dn + b2[c0])     : -3.4e38f;
    float v1 = (c0 + 1 < F_OUT) ? (a[1] * dn + b2[c0 + 1]) : -3.4e38f;
    float v2 = (c0 + 2 < F_OUT) ? (a[2] * dn + b2[c0 + 2]) : -3.4e38f;
    float v3 = (c0 + 3 < F_OUT) ? (a[3] * dn + b2[c0 + 3]) : -3.4e38f;
    float m = fmaxf(fmaxf(v0, v1), fmaxf(v2, v3));
    #pragma unroll
    for (int o = 8; o > 0; o >>= 1) m = fmaxf(m, __shfl_xor(m, o));
    float ex = ((c0 < F_OUT)     ? __expf(v0 - m) : 0.0f)
             + ((c0 + 1 < F_OUT) ? __expf(v1 - m) : 0.0f)
             + ((c0 + 2 < F_OUT) ? __expf(v2 - m) : 0.0f)
             + ((c0 + 3 < F_OUT) ? __expf(v3 - m) : 0.0f);
    #pragma unroll
    for (int o = 8; o > 0; o >>= 1) ex += __shfl_xor(ex, o);
    float ls = __logf(ex);
    if (q == 0 && c0 < F_OUT) {
        float4 o4 = make_float4(v0 - m - ls, v1 - m - ls, v2 - m - ls, v3 - m - ls);
        *(float4*)(out + (size_t)node * F_OUT + c0) = o4;
    }
}

// ---------------- launch ----------------
static inline char* alignup(char* p) {
    return (char*)(((uintptr_t)p + 255) & ~(uintptr_t)255);
}

extern "C" void kernel_launch(void* const* d_in, const int* in_sizes, int n_in,
                              void* d_out, int out_size, void* d_ws, size_t ws_size,
                              hipStream_t stream) {
    const float* x  = (const float*)d_in[0];
    const int*   ei = (const int*)d_in[1];
    const float* W1 = (const float*)d_in[2];
    const float* b1 = (const float*)d_in[3];
    const float* W2 = (const float*)d_in[4];
    const float* b2 = (const float*)d_in[5];
    float* out = (float*)d_out;

    char* w = (char*)d_ws;
    int* gtot  = (int*)w;             w = alignup(w + (size_t)NBKT * 4);
    int* boff  = (int*)w;             w = alignup(w + (size_t)(NBKT + 1) * 4);
    int* bcur  = (int*)w;             w = alignup(w + (size_t)NBKT * 4);
    int* off   = (int*)w;             w = alignup(w + (size_t)(N_NODES + 1) * 4);
    float* dinv = (float*)w;          w = alignup(w + (size_t)N_NODES * 4);
    int2* edges = (int2*)w;           w = alignup(w + (size_t)N_EDGES * 8);
    unsigned short* W1t = (unsigned short*)w;  w = alignup(w + (size_t)F_HID * F_IN * 2);
    unsigned short* W2t = (unsigned short*)w;  w = alignup(w + (size_t)F_OUT_P * F_HID * 2);
    unsigned char* h    = (unsigned char*)w;   w = alignup(w + (size_t)N_NODES * F_HID);      // fp8
    unsigned short* h1  = (unsigned short*)w;  w = alignup(w + (size_t)N_NODES * F_HID * 2);
    unsigned short* h2  = (unsigned short*)w;  w = alignup(w + (size_t)N_NODES * F_OUT_P * 2);
    // lifetime-disjoint aliases (binned dead before gemm1 writes h; ssrc dead before agg1 writes h1)
    unsigned int* binned = (unsigned int*)h;   // 6.4 MB < 12.8 MB
    int* ssrc            = (int*)h1;           // 6.4 MB < 25.6 MB

    const int* srcp = ei;
    const int* dstp = ei + N_EDGES;

    hipMemsetAsync(gtot, 0, (size_t)NBKT * 4, stream);
    k_hist<<<P1_NBLK, 256, 0, stream>>>(dstp, gtot);
    k_bktscan<<<1, 256, 0, stream>>>(gtot, boff, bcur);
    k_bin<<<P1_NBLK, 256, 0, stream>>>(srcp, dstp, bcur, binned);
    k_place<<<NBKT, 256, 0, stream>>>(binned, boff, off, dinv, ssrc);
    k_mkrec<<<(N_EDGES / 4 + 255) / 256, 256, 0, stream>>>(ssrc, dinv, edges);

    k_convW<<<(F_IN * F_HID + F_OUT_P * F_HID + 255) / 256, 256, 0, stream>>>(W1, W2, W1t, W2t);

    k_gemm1<<<(N_NODES + 127) / 128, 256, 0, stream>>>(x, W1t, h);
    k_agg1<<<(N_NODES + 3) / 4, 256, 0, stream>>>(h, off, edges, dinv, b1, h1);
    k_gemm2<<<(N_NODES + 127) / 128, 256, 0, stream>>>(h1, W2t, h2);
    k_agg2<<<(N_NODES + 3) / 4, 256, 0, stream>>>(h2, off, edges, dinv, b2, out);
}

// Round 8
// 394.046 us; speedup vs baseline: 1.1190x; 1.1190x over previous
//
#include <hip/hip_runtime.h>
#include <cstdint>
#include <cstddef>

#define N_NODES 100000
#define N_EDGES 1600000
#define F_IN 256
#define F_HID 128
#define F_OUT 40
#define F_OUT_P 64   // h2 padded cols (bf16)

#define BKT_SHIFT 8
#define BKT_SIZE 256
#define NBKT ((N_NODES + BKT_SIZE - 1) / BKT_SIZE)   // 391
#define P1_EPT 16
#define P1_EPB (256 * P1_EPT)                        // 4096 edges/block
#define P1_NBLK ((N_EDGES + P1_EPB - 1) / P1_EPB)    // 391

typedef __attribute__((ext_vector_type(8))) short short8;
typedef __attribute__((ext_vector_type(4))) float floatx4;
typedef __attribute__((ext_vector_type(2))) float floatx2;

__device__ __forceinline__ float bf2f(unsigned short u) {
    return __uint_as_float(((unsigned int)u) << 16);
}
__device__ __forceinline__ unsigned short f2bf(float f) {
    unsigned int x = __float_as_uint(f);
    x += 0x7fffu + ((x >> 16) & 1u);   // RNE
    return (unsigned short)(x >> 16);
}
__device__ __forceinline__ float lo16(unsigned int u) { return __uint_as_float(u << 16); }
__device__ __forceinline__ float hi16(unsigned int u) { return __uint_as_float(u & 0xFFFF0000u); }
__device__ __forceinline__ unsigned char f2fp8(float v) {
    return (unsigned char)(__builtin_amdgcn_cvt_pk_fp8_f32(v, v, 0, false) & 0xFF);
}

// ---------------- P1a: bucket histogram ----------------
__global__ __launch_bounds__(256) void k_hist(const int* __restrict__ dst,
                                              int* __restrict__ gtot) {
    __shared__ int hist[NBKT];
    for (int i = threadIdx.x; i < NBKT; i += 256) hist[i] = 0;
    __syncthreads();
    int base = blockIdx.x * P1_EPB;
    #pragma unroll
    for (int i = 0; i < P1_EPT; ++i) {
        int e = base + threadIdx.x + i * 256;
        if (e < N_EDGES) atomicAdd(&hist[dst[e] >> BKT_SHIFT], 1);
    }
    __syncthreads();
    for (int i = threadIdx.x; i < NBKT; i += 256)
        if (hist[i]) atomicAdd(&gtot[i], hist[i]);
}

// ---------------- P1b: scan bucket totals ----------------
__global__ __launch_bounds__(256) void k_bktscan(const int* __restrict__ gtot,
                                                 int* __restrict__ boff,
                                                 int* __restrict__ bcur) {
    __shared__ int lds[NBKT + 1];
    int t = threadIdx.x;
    for (int i = t; i < NBKT; i += 256) lds[i] = gtot[i];
    __syncthreads();
    if (t == 0) {
        int run = 0;
        for (int i = 0; i < NBKT; ++i) { int v = lds[i]; lds[i] = run; run += v; }
        lds[NBKT] = run;
    }
    __syncthreads();
    for (int i = t; i <= NBKT; i += 256) {
        boff[i] = lds[i];
        if (i < NBKT) bcur[i] = lds[i];
    }
}

// ---------------- P1c: bin edges by bucket (4B packed records) ----------------
__global__ __launch_bounds__(256) void k_bin(const int* __restrict__ src,
                                             const int* __restrict__ dst,
                                             int* __restrict__ bcur,
                                             unsigned int* __restrict__ binned) {
    __shared__ int hist[NBKT];
    __shared__ int baseg[NBKT];
    __shared__ int cnt2[NBKT];
    for (int i = threadIdx.x; i < NBKT; i += 256) { hist[i] = 0; cnt2[i] = 0; }
    __syncthreads();
    int base = blockIdx.x * P1_EPB;
    int s[P1_EPT], d[P1_EPT];
    #pragma unroll
    for (int i = 0; i < P1_EPT; ++i) {
        int e = base + threadIdx.x + i * 256;
        if (e < N_EDGES) {
            s[i] = src[e]; d[i] = dst[e];
            atomicAdd(&hist[d[i] >> BKT_SHIFT], 1);
        } else d[i] = -1;
    }
    __syncthreads();
    for (int i = threadIdx.x; i < NBKT; i += 256)
        baseg[i] = hist[i] ? atomicAdd(&bcur[i], hist[i]) : 0;
    __syncthreads();
    #pragma unroll
    for (int i = 0; i < P1_EPT; ++i) {
        if (d[i] >= 0) {
            int b = d[i] >> BKT_SHIFT;
            int r = atomicAdd(&cnt2[b], 1);
            binned[baseg[b] + r] =
                (unsigned int)s[i] | ((unsigned int)(d[i] & (BKT_SIZE - 1)) << 17);
        }
    }
}

// ---------------- P2: per-bucket place -> CSR, off[], dinv[] (no global atomics) ----------------
__global__ __launch_bounds__(256) void k_place(const unsigned int* __restrict__ binned,
                                               const int* __restrict__ boff,
                                               int* __restrict__ off,
                                               float* __restrict__ dinv,
                                               int* __restrict__ ssrc) {
    __shared__ int cnt[BKT_SIZE];
    __shared__ int ioff[BKT_SIZE];
    __shared__ int sexcl[BKT_SIZE];
    int b = blockIdx.x, t = threadIdx.x;
    int e0 = boff[b], e1 = boff[b + 1];
    cnt[t] = 0;
    __syncthreads();
    for (int i = e0 + t; i < e1; i += 256)
        atomicAdd(&cnt[binned[i] >> 17], 1);
    __syncthreads();
    int v = cnt[t];
    ioff[t] = v;
    __syncthreads();
    for (int ofs = 1; ofs < 256; ofs <<= 1) {
        int y = (t >= ofs) ? ioff[t - ofs] : 0;
        __syncthreads();
        ioff[t] += y;
        __syncthreads();
    }
    int excl = ioff[t] - v;   // exclusive prefix within bucket
    int n = b * BKT_SIZE + t;
    if (n < N_NODES) {
        off[n] = e0 + excl;
        dinv[n] = rsqrtf((float)v + 1.0f);
    }
    if (b == NBKT - 1 && t == 0) off[N_NODES] = N_EDGES;
    __syncthreads();
    cnt[t] = 0;
    sexcl[t] = excl;
    __syncthreads();
    for (int i = e0 + t; i < e1; i += 256) {
        unsigned int rec = binned[i];
        int dl = rec >> 17;
        int r = atomicAdd(&cnt[dl], 1);
        ssrc[e0 + sexcl[dl] + r] = (int)(rec & 0x1FFFFu);
    }
}

// ---------------- P3: build (src, dinv[src]) records ----------------
__global__ __launch_bounds__(256) void k_mkrec(const int* __restrict__ ssrc,
                                               const float* __restrict__ dinv,
                                               int2* __restrict__ edges) {
    int i = blockIdx.x * blockDim.x + threadIdx.x;   // groups of 4
    if (i < N_EDGES / 4) {
        int4 s4 = ((const int4*)ssrc)[i];
        int4* ep = (int4*)(edges + (size_t)i * 4);
        ep[0] = make_int4(s4.x, __float_as_int(dinv[s4.x]),
                          s4.y, __float_as_int(dinv[s4.y]));
        ep[1] = make_int4(s4.z, __float_as_int(dinv[s4.z]),
                          s4.w, __float_as_int(dinv[s4.w]));
    }
}

// ---------------- weight conversion (merged) ----------------
__global__ void k_convW(const float* __restrict__ W1, const float* __restrict__ W2,
                        unsigned short* __restrict__ W1t, unsigned short* __restrict__ W2t) {
    int i = blockIdx.x * blockDim.x + threadIdx.x;
    if (i < F_IN * F_HID) {
        int k = i >> 7, n = i & 127;
        W1t[n * F_IN + k] = f2bf(W1[i]);
    } else {
        int j = i - F_IN * F_HID;
        if (j < F_OUT_P * F_HID) {
            int k = j >> 6, n = j & 63;
            float v = (n < F_OUT) ? W2[k * F_OUT + n] : 0.0f;
            W2t[n * F_HID + k] = f2bf(v);
        }
    }
}

// ---------------- GEMM1 (MFMA bf16): x[N,256]f32 @ W1 -> h[N,128] fp8-e4m3 ----------------
__global__ __launch_bounds__(256) void k_gemm1(const float* __restrict__ A,
                                               const unsigned short* __restrict__ Wt,
                                               unsigned char* __restrict__ C) {
    __shared__ unsigned short As[128][40];
    __shared__ unsigned short Ws[128][40];
    int t = threadIdx.x;
    int wave = t >> 6, lane = t & 63;
    int quad = lane >> 4, l16 = lane & 15;
    int row0 = blockIdx.x * 128;
    floatx4 acc[2][8];
    #pragma unroll
    for (int i = 0; i < 2; ++i)
        #pragma unroll
        for (int j = 0; j < 8; ++j)
            #pragma unroll
            for (int r = 0; r < 4; ++r) acc[i][j][r] = 0.0f;

    for (int k0 = 0; k0 < F_IN; k0 += 32) {
        #pragma unroll
        for (int i = 0; i < 4; ++i) {
            int idx = t + i * 256;
            int r = idx >> 3, c = idx & 7;
            int gr = row0 + r; if (gr > N_NODES - 1) gr = N_NODES - 1;
            float4 va = *(const float4*)(A + (size_t)gr * F_IN + k0 + c * 4);
            ushort4 u;
            u.x = f2bf(va.x); u.y = f2bf(va.y); u.z = f2bf(va.z); u.w = f2bf(va.w);
            *(ushort4*)(&As[r][c * 4]) = u;
        }
        #pragma unroll
        for (int i = 0; i < 2; ++i) {
            int idx = t + i * 256;
            int n = idx >> 2, c = idx & 3;
            ushort4 w0 = *(const ushort4*)(Wt + (size_t)n * F_IN + k0 + c * 8);
            ushort4 w1 = *(const ushort4*)(Wt + (size_t)n * F_IN + k0 + c * 8 + 4);
            *(ushort4*)(&Ws[n][c * 8]) = w0;
            *(ushort4*)(&Ws[n][c * 8 + 4]) = w1;
        }
        __syncthreads();
        short8 af[2];
        #pragma unroll
        for (int rt = 0; rt < 2; ++rt)
            af[rt] = *(const short8*)(&As[wave * 32 + rt * 16 + l16][quad * 8]);
        #pragma unroll
        for (int ct = 0; ct < 8; ++ct) {
            short8 bf = *(const short8*)(&Ws[ct * 16 + l16][quad * 8]);
            acc[0][ct] = __builtin_amdgcn_mfma_f32_16x16x32_bf16(af[0], bf, acc[0][ct], 0, 0, 0);
            acc[1][ct] = __builtin_amdgcn_mfma_f32_16x16x32_bf16(af[1], bf, acc[1][ct], 0, 0, 0);
        }
        __syncthreads();
    }
    #pragma unroll
    for (int rt = 0; rt < 2; ++rt) {
        #pragma unroll
        for (int ct = 0; ct < 8; ++ct) {
            #pragma unroll
            for (int r = 0; r < 4; ++r) {
                int row = row0 + wave * 32 + rt * 16 + quad * 4 + r;
                if (row < N_NODES)
                    C[(size_t)row * F_HID + ct * 16 + l16] = f2fp8(acc[rt][ct][r]);
            }
        }
    }
}

// ---------------- agg1: h (fp8) gather, 4 quarter-waves x 4 edges in flight ----------------
#define ACCF8(u2, wgt) { \
    floatx2 p0 = __builtin_amdgcn_cvt_pk_f32_fp8(u2.x, false); \
    floatx2 p1 = __builtin_amdgcn_cvt_pk_f32_fp8(u2.x, true); \
    floatx2 p2 = __builtin_amdgcn_cvt_pk_f32_fp8(u2.y, false); \
    floatx2 p3 = __builtin_amdgcn_cvt_pk_f32_fp8(u2.y, true); \
    a[0] += wgt * p0.x; a[1] += wgt * p0.y; a[2] += wgt * p1.x; a[3] += wgt * p1.y; \
    a[4] += wgt * p2.x; a[5] += wgt * p2.y; a[6] += wgt * p3.x; a[7] += wgt * p3.y; }

__global__ __launch_bounds__(256) void k_agg1(const unsigned char* __restrict__ h_,
                                              const int* __restrict__ off,
                                              const int2* __restrict__ edges,
                                              const float* __restrict__ dinv,
                                              const float* __restrict__ b1,
                                              unsigned short* __restrict__ h1_) {
    const uint2* h = (const uint2*)h_;   // row = 16 uint2 (128 fp8)
    uint4* h1 = (uint4*)h1_;
    int node = blockIdx.x * 4 + (threadIdx.x >> 6);
    int lane = threadIdx.x & 63;
    int q = lane >> 4, l16 = lane & 15;
    if (node >= N_NODES) return;
    int s0 = off[node], s1 = off[node + 1];
    int nE = s1 - s0;
    float dn = dinv[node];
    float a[8] = {};
    if (q == 0) {
        uint2 sv = h[(size_t)node * 16 + l16];
        ACCF8(sv, dn);
    }
    int end4 = s0 + (nE & ~3);
    int e = s0 + q;
    for (; e + 12 < end4; e += 16) {
        int2 r0 = edges[e], r1 = edges[e + 4], r2 = edges[e + 8], r3 = edges[e + 12];
        uint2 v0 = h[(size_t)r0.x * 16 + l16];
        uint2 v1 = h[(size_t)r1.x * 16 + l16];
        uint2 v2 = h[(size_t)r2.x * 16 + l16];
        uint2 v3 = h[(size_t)r3.x * 16 + l16];
        ACCF8(v0, __int_as_float(r0.y));
        ACCF8(v1, __int_as_float(r1.y));
        ACCF8(v2, __int_as_float(r2.y));
        ACCF8(v3, __int_as_float(r3.y));
    }
    for (; e < end4; e += 4) {
        int2 r0 = edges[e];
        uint2 v0 = h[(size_t)r0.x * 16 + l16];
        ACCF8(v0, __int_as_float(r0.y));
    }
    if (q < (nE & 3)) {
        int2 r0 = edges[end4 + q];
        uint2 v0 = h[(size_t)r0.x * 16 + l16];
        ACCF8(v0, __int_as_float(r0.y));
    }
    #pragma unroll
    for (int i = 0; i < 8; ++i) {
        a[i] += __shfl_xor(a[i], 16);
        a[i] += __shfl_xor(a[i], 32);
    }
    if (q == 0) {
        float4 bb0 = ((const float4*)b1)[l16 * 2];
        float4 bb1 = ((const float4*)b1)[l16 * 2 + 1];
        unsigned short c0 = f2bf(fmaxf(a[0] * dn + bb0.x, 0.0f));
        unsigned short c1 = f2bf(fmaxf(a[1] * dn + bb0.y, 0.0f));
        unsigned short c2 = f2bf(fmaxf(a[2] * dn + bb0.z, 0.0f));
        unsigned short c3 = f2bf(fmaxf(a[3] * dn + bb0.w, 0.0f));
        unsigned short c4 = f2bf(fmaxf(a[4] * dn + bb1.x, 0.0f));
        unsigned short c5 = f2bf(fmaxf(a[5] * dn + bb1.y, 0.0f));
        unsigned short c6 = f2bf(fmaxf(a[6] * dn + bb1.z, 0.0f));
        unsigned short c7 = f2bf(fmaxf(a[7] * dn + bb1.w, 0.0f));
        uint4 r;
        r.x = (unsigned int)c0 | ((unsigned int)c1 << 16);
        r.y = (unsigned int)c2 | ((unsigned int)c3 << 16);
        r.z = (unsigned int)c4 | ((unsigned int)c5 << 16);
        r.w = (unsigned int)c6 | ((unsigned int)c7 << 16);
        h1[(size_t)node * 16 + l16] = r;
    }
}

// ---------------- GEMM2 (MFMA bf16): h1[N,128]bf16 @ W2 -> h2[N,64]bf16 ----------------
__global__ __launch_bounds__(256) void k_gemm2(const unsigned short* __restrict__ A,
                                               const unsigned short* __restrict__ Wt,
                                               unsigned short* __restrict__ C) {
    __shared__ unsigned short As[128][136];
    __shared__ unsigned short Ws[64][136];
    int t = threadIdx.x;
    int wave = t >> 6, lane = t & 63;
    int quad = lane >> 4, l16 = lane & 15;
    int row0 = blockIdx.x * 128;
    floatx4 acc[2][4];
    #pragma unroll
    for (int i = 0; i < 2; ++i)
        #pragma unroll
        for (int j = 0; j < 4; ++j)
            #pragma unroll
            for (int r = 0; r < 4; ++r) acc[i][j][r] = 0.0f;

    #pragma unroll
    for (int i = 0; i < 8; ++i) {
        int idx = t + i * 256;
        int r = idx >> 4, c = idx & 15;
        int gr = row0 + r; if (gr > N_NODES - 1) gr = N_NODES - 1;
        ushort4 w0 = *(const ushort4*)(A + (size_t)gr * F_HID + c * 8);
        ushort4 w1 = *(const ushort4*)(A + (size_t)gr * F_HID + c * 8 + 4);
        *(ushort4*)(&As[r][c * 8]) = w0;
        *(ushort4*)(&As[r][c * 8 + 4]) = w1;
    }
    #pragma unroll
    for (int i = 0; i < 4; ++i) {
        int idx = t + i * 256;
        int n = idx >> 4, c = idx & 15;
        ushort4 w0 = *(const ushort4*)(Wt + (size_t)n * F_HID + c * 8);
        ushort4 w1 = *(const ushort4*)(Wt + (size_t)n * F_HID + c * 8 + 4);
        *(ushort4*)(&Ws[n][c * 8]) = w0;
        *(ushort4*)(&Ws[n][c * 8 + 4]) = w1;
    }
    __syncthreads();
    #pragma unroll
    for (int ks = 0; ks < 4; ++ks) {
        int k0 = ks * 32;
        short8 af[2];
        #pragma unroll
        for (int rt = 0; rt < 2; ++rt)
            af[rt] = *(const short8*)(&As[wave * 32 + rt * 16 + l16][k0 + quad * 8]);
        #pragma unroll
        for (int ct = 0; ct < 4; ++ct) {
            short8 bf = *(const short8*)(&Ws[ct * 16 + l16][k0 + quad * 8]);
            acc[0][ct] = __builtin_amdgcn_mfma_f32_16x16x32_bf16(af[0], bf, acc[0][ct], 0, 0, 0);
            acc[1][ct] = __builtin_amdgcn_mfma_f32_16x16x32_bf16(af[1], bf, acc[1][ct], 0, 0, 0);
        }
    }
    #pragma unroll
    for (int rt = 0; rt < 2; ++rt) {
        #pragma unroll
        for (int ct = 0; ct < 4; ++ct) {
            #pragma unroll
            for (int r = 0; r < 4; ++r) {
                int row = row0 + wave * 32 + rt * 16 + quad * 4 + r;
                if (row < N_NODES)
                    C[(size_t)row * F_OUT_P + ct * 16 + l16] = f2bf(acc[rt][ct][r]);
            }
        }
    }
}

// ---------------- agg2 + bias + log_softmax: 8 eighth-waves x 2 unroll = 16 in flight ----------------
// group g = lane>>3 handles edges e = s0+g, step 8; lane loads uint4 (8 bf16 cols).
#define ACC8B(u4, wgt) { \
    a[0] += wgt * lo16(u4.x); a[1] += wgt * hi16(u4.x); \
    a[2] += wgt * lo16(u4.y); a[3] += wgt * hi16(u4.y); \
    a[4] += wgt * lo16(u4.z); a[5] += wgt * hi16(u4.z); \
    a[6] += wgt * lo16(u4.w); a[7] += wgt * hi16(u4.w); }

__global__ __launch_bounds__(256) void k_agg2(const unsigned short* __restrict__ h2_,
                                              const int* __restrict__ off,
                                              const int2* __restrict__ edges,
                                              const float* __restrict__ dinv,
                                              const float* __restrict__ b2,
                                              float* __restrict__ out) {
    const uint4* h2 = (const uint4*)h2_;  // row = 8 uint4 (64 bf16)
    int node = blockIdx.x * 4 + (threadIdx.x >> 6);
    int lane = threadIdx.x & 63;
    int g = lane >> 3, l8 = lane & 7;
    if (node >= N_NODES) return;
    int s0 = off[node], s1 = off[node + 1];
    int nE = s1 - s0;
    float dn = dinv[node];
    float a[8] = {};
    if (g == 0) {
        uint4 sv = h2[(size_t)node * 8 + l8];
        ACC8B(sv, dn);
    }
    int end8 = s0 + (nE & ~7);
    int e = s0 + g;
    for (; e + 8 < end8; e += 16) {
        int2 r0 = edges[e], r1 = edges[e + 8];
        uint4 v0 = h2[(size_t)r0.x * 8 + l8];
        uint4 v1 = h2[(size_t)r1.x * 8 + l8];
        ACC8B(v0, __int_as_float(r0.y));
        ACC8B(v1, __int_as_float(r1.y));
    }
    for (; e < end8; e += 8) {
        int2 r0 = edges[e];
        uint4 v0 = h2[(size_t)r0.x * 8 + l8];
        ACC8B(v0, __int_as_float(r0.y));
    }
    if (g < (nE & 7)) {
        int2 r0 = edges[end8 + g];
        uint4 v0 = h2[(size_t)r0.x * 8 + l8];
        ACC8B(v0, __int_as_float(r0.y));
    }
    #pragma unroll
    for (int i = 0; i < 8; ++i) {
        a[i] += __shfl_xor(a[i], 8);
        a[i] += __shfl_xor(a[i], 16);
        a[i] += __shfl_xor(a[i], 32);
    }
    // lanes with same l8 hold identical sums for cols 8*l8 .. 8*l8+7
    int c0 = l8 * 8;
    float v[8];
    #pragma unroll
    for (int j = 0; j < 8; ++j)
        v[j] = (c0 + j < F_OUT) ? (a[j] * dn + b2[c0 + j]) : -3.4e38f;
    float m = v[0];
    #pragma unroll
    for (int j = 1; j < 8; ++j) m = fmaxf(m, v[j]);
    #pragma unroll
    for (int o = 4; o > 0; o >>= 1) m = fmaxf(m, __shfl_xor(m, o));
    float ex = 0.0f;
    #pragma unroll
    for (int j = 0; j < 8; ++j)
        if (c0 + j < F_OUT) ex += __expf(v[j] - m);
    #pragma unroll
    for (int o = 4; o > 0; o >>= 1) ex += __shfl_xor(ex, o);
    float ls = __logf(ex);
    if (g == 0 && c0 < F_OUT) {
        float4 o0 = make_float4(v[0] - m - ls, v[1] - m - ls, v[2] - m - ls, v[3] - m - ls);
        float4 o1 = make_float4(v[4] - m - ls, v[5] - m - ls, v[6] - m - ls, v[7] - m - ls);
        *(float4*)(out + (size_t)node * F_OUT + c0) = o0;
        *(float4*)(out + (size_t)node * F_OUT + c0 + 4) = o1;
    }
}

// ---------------- launch ----------------
static inline char* alignup(char* p) {
    return (char*)(((uintptr_t)p + 255) & ~(uintptr_t)255);
}

extern "C" void kernel_launch(void* const* d_in, const int* in_sizes, int n_in,
                              void* d_out, int out_size, void* d_ws, size_t ws_size,
                              hipStream_t stream) {
    const float* x  = (const float*)d_in[0];
    const int*   ei = (const int*)d_in[1];
    const float* W1 = (const float*)d_in[2];
    const float* b1 = (const float*)d_in[3];
    const float* W2 = (const float*)d_in[4];
    const float* b2 = (const float*)d_in[5];
    float* out = (float*)d_out;

    char* w = (char*)d_ws;
    int* gtot  = (int*)w;             w = alignup(w + (size_t)NBKT * 4);
    int* boff  = (int*)w;             w = alignup(w + (size_t)(NBKT + 1) * 4);
    int* bcur  = (int*)w;             w = alignup(w + (size_t)NBKT * 4);
    int* off   = (int*)w;             w = alignup(w + (size_t)(N_NODES + 1) * 4);
    float* dinv = (float*)w;          w = alignup(w + (size_t)N_NODES * 4);
    int2* edges = (int2*)w;           w = alignup(w + (size_t)N_EDGES * 8);
    unsigned short* W1t = (unsigned short*)w;  w = alignup(w + (size_t)F_HID * F_IN * 2);
    unsigned short* W2t = (unsigned short*)w;  w = alignup(w + (size_t)F_OUT_P * F_HID * 2);
    unsigned char* h    = (unsigned char*)w;   w = alignup(w + (size_t)N_NODES * F_HID);      // fp8
    unsigned short* h1  = (unsigned short*)w;  w = alignup(w + (size_t)N_NODES * F_HID * 2);
    unsigned short* h2  = (unsigned short*)w;  w = alignup(w + (size_t)N_NODES * F_OUT_P * 2);
    // lifetime-disjoint aliases (binned dead before gemm1 writes h; ssrc dead before agg1 writes h1)
    unsigned int* binned = (unsigned int*)h;   // 6.4 MB < 12.8 MB
    int* ssrc            = (int*)h1;           // 6.4 MB < 25.6 MB

    const int* srcp = ei;
    const int* dstp = ei + N_EDGES;

    hipMemsetAsync(gtot, 0, (size_t)NBKT * 4, stream);
    k_hist<<<P1_NBLK, 256, 0, stream>>>(dstp, gtot);
    k_bktscan<<<1, 256, 0, stream>>>(gtot, boff, bcur);
    k_bin<<<P1_NBLK, 256, 0, stream>>>(srcp, dstp, bcur, binned);
    k_place<<<NBKT, 256, 0, stream>>>(binned, boff, off, dinv, ssrc);
    k_mkrec<<<(N_EDGES / 4 + 255) / 256, 256, 0, stream>>>(ssrc, dinv, edges);

    k_convW<<<(F_IN * F_HID + F_OUT_P * F_HID + 255) / 256, 256, 0, stream>>>(W1, W2, W1t, W2t);

    k_gemm1<<<(N_NODES + 127) / 128, 256, 0, stream>>>(x, W1t, h);
    k_agg1<<<(N_NODES + 3) / 4, 256, 0, stream>>>(h, off, edges, dinv, b1, h1);
    k_gemm2<<<(N_NODES + 127) / 128, 256, 0, stream>>>(h1, W2t, h2);
    k_agg2<<<(N_NODES + 3) / 4, 256, 0, stream>>>(h2, off, edges, dinv, b2, out);
}

// Round 9
// 390.067 us; speedup vs baseline: 1.1304x; 1.0102x over previous
//
#include <hip/hip_runtime.h>
#include <cstdint>
#include <cstddef>

#define N_NODES 100000
#define N_EDGES 1600000
#define F_IN 256
#define F_HID 128
#define F_OUT 40
#define F_OUT_P 64   // h2 padded cols (fp8)

#define BKT_SHIFT 8
#define BKT_SIZE 256
#define NBKT ((N_NODES + BKT_SIZE - 1) / BKT_SIZE)   // 391
#define P1_EPT 16
#define P1_EPB (256 * P1_EPT)                        // 4096 edges/block
#define P1_NBLK ((N_EDGES + P1_EPB - 1) / P1_EPB)    // 391

typedef __attribute__((ext_vector_type(8))) short short8;
typedef __attribute__((ext_vector_type(4))) float floatx4;
typedef __attribute__((ext_vector_type(2))) float floatx2;

__device__ __forceinline__ float bf2f(unsigned short u) {
    return __uint_as_float(((unsigned int)u) << 16);
}
__device__ __forceinline__ unsigned short f2bf(float f) {
    unsigned int x = __float_as_uint(f);
    x += 0x7fffu + ((x >> 16) & 1u);   // RNE
    return (unsigned short)(x >> 16);
}
__device__ __forceinline__ float lo16(unsigned int u) { return __uint_as_float(u << 16); }
__device__ __forceinline__ float hi16(unsigned int u) { return __uint_as_float(u & 0xFFFF0000u); }
__device__ __forceinline__ unsigned char f2fp8(float v) {
    return (unsigned char)(__builtin_amdgcn_cvt_pk_fp8_f32(v, v, 0, false) & 0xFF);
}

// ---------------- P1a: bucket histogram ----------------
__global__ __launch_bounds__(256) void k_hist(const int* __restrict__ dst,
                                              int* __restrict__ gtot) {
    __shared__ int hist[NBKT];
    for (int i = threadIdx.x; i < NBKT; i += 256) hist[i] = 0;
    __syncthreads();
    int base = blockIdx.x * P1_EPB;
    #pragma unroll
    for (int i = 0; i < P1_EPT; ++i) {
        int e = base + threadIdx.x + i * 256;
        if (e < N_EDGES) atomicAdd(&hist[dst[e] >> BKT_SHIFT], 1);
    }
    __syncthreads();
    for (int i = threadIdx.x; i < NBKT; i += 256)
        if (hist[i]) atomicAdd(&gtot[i], hist[i]);
}

// ---------------- P1b: scan bucket totals ----------------
__global__ __launch_bounds__(256) void k_bktscan(const int* __restrict__ gtot,
                                                 int* __restrict__ boff,
                                                 int* __restrict__ bcur) {
    __shared__ int lds[NBKT + 1];
    int t = threadIdx.x;
    for (int i = t; i < NBKT; i += 256) lds[i] = gtot[i];
    __syncthreads();
    if (t == 0) {
        int run = 0;
        for (int i = 0; i < NBKT; ++i) { int v = lds[i]; lds[i] = run; run += v; }
        lds[NBKT] = run;
    }
    __syncthreads();
    for (int i = t; i <= NBKT; i += 256) {
        boff[i] = lds[i];
        if (i < NBKT) bcur[i] = lds[i];
    }
}

// ---------------- P1c: bin edges by bucket (4B packed records) ----------------
__global__ __launch_bounds__(256) void k_bin(const int* __restrict__ src,
                                             const int* __restrict__ dst,
                                             int* __restrict__ bcur,
                                             unsigned int* __restrict__ binned) {
    __shared__ int hist[NBKT];
    __shared__ int baseg[NBKT];
    __shared__ int cnt2[NBKT];
    for (int i = threadIdx.x; i < NBKT; i += 256) { hist[i] = 0; cnt2[i] = 0; }
    __syncthreads();
    int base = blockIdx.x * P1_EPB;
    int s[P1_EPT], d[P1_EPT];
    #pragma unroll
    for (int i = 0; i < P1_EPT; ++i) {
        int e = base + threadIdx.x + i * 256;
        if (e < N_EDGES) {
            s[i] = src[e]; d[i] = dst[e];
            atomicAdd(&hist[d[i] >> BKT_SHIFT], 1);
        } else d[i] = -1;
    }
    __syncthreads();
    for (int i = threadIdx.x; i < NBKT; i += 256)
        baseg[i] = hist[i] ? atomicAdd(&bcur[i], hist[i]) : 0;
    __syncthreads();
    #pragma unroll
    for (int i = 0; i < P1_EPT; ++i) {
        if (d[i] >= 0) {
            int b = d[i] >> BKT_SHIFT;
            int r = atomicAdd(&cnt2[b], 1);
            binned[baseg[b] + r] =
                (unsigned int)s[i] | ((unsigned int)(d[i] & (BKT_SIZE - 1)) << 17);
        }
    }
}

// ---------------- P2: per-bucket place -> CSR, off[], dinv[] (no global atomics) ----------------
__global__ __launch_bounds__(256) void k_place(const unsigned int* __restrict__ binned,
                                               const int* __restrict__ boff,
                                               int* __restrict__ off,
                                               float* __restrict__ dinv,
                                               int* __restrict__ ssrc) {
    __shared__ int cnt[BKT_SIZE];
    __shared__ int ioff[BKT_SIZE];
    __shared__ int sexcl[BKT_SIZE];
    int b = blockIdx.x, t = threadIdx.x;
    int e0 = boff[b], e1 = boff[b + 1];
    cnt[t] = 0;
    __syncthreads();
    for (int i = e0 + t; i < e1; i += 256)
        atomicAdd(&cnt[binned[i] >> 17], 1);
    __syncthreads();
    int v = cnt[t];
    ioff[t] = v;
    __syncthreads();
    for (int ofs = 1; ofs < 256; ofs <<= 1) {
        int y = (t >= ofs) ? ioff[t - ofs] : 0;
        __syncthreads();
        ioff[t] += y;
        __syncthreads();
    }
    int excl = ioff[t] - v;   // exclusive prefix within bucket
    int n = b * BKT_SIZE + t;
    if (n < N_NODES) {
        off[n] = e0 + excl;
        dinv[n] = rsqrtf((float)v + 1.0f);
    }
    if (b == NBKT - 1 && t == 0) off[N_NODES] = N_EDGES;
    __syncthreads();
    cnt[t] = 0;
    sexcl[t] = excl;
    __syncthreads();
    for (int i = e0 + t; i < e1; i += 256) {
        unsigned int rec = binned[i];
        int dl = rec >> 17;
        int r = atomicAdd(&cnt[dl], 1);
        ssrc[e0 + sexcl[dl] + r] = (int)(rec & 0x1FFFFu);
    }
}

// ---------------- P3: build (src, dinv[src]) records ----------------
__global__ __launch_bounds__(256) void k_mkrec(const int* __restrict__ ssrc,
                                               const float* __restrict__ dinv,
                                               int2* __restrict__ edges) {
    int i = blockIdx.x * blockDim.x + threadIdx.x;   // groups of 4
    if (i < N_EDGES / 4) {
        int4 s4 = ((const int4*)ssrc)[i];
        int4* ep = (int4*)(edges + (size_t)i * 4);
        ep[0] = make_int4(s4.x, __float_as_int(dinv[s4.x]),
                          s4.y, __float_as_int(dinv[s4.y]));
        ep[1] = make_int4(s4.z, __float_as_int(dinv[s4.z]),
                          s4.w, __float_as_int(dinv[s4.w]));
    }
}

// ---------------- weight conversion (merged) ----------------
__global__ void k_convW(const float* __restrict__ W1, const float* __restrict__ W2,
                        unsigned short* __restrict__ W1t, unsigned short* __restrict__ W2t) {
    int i = blockIdx.x * blockDim.x + threadIdx.x;
    if (i < F_IN * F_HID) {
        int k = i >> 7, n = i & 127;
        W1t[n * F_IN + k] = f2bf(W1[i]);
    } else {
        int j = i - F_IN * F_HID;
        if (j < F_OUT_P * F_HID) {
            int k = j >> 6, n = j & 63;
            float v = (n < F_OUT) ? W2[k * F_OUT + n] : 0.0f;
            W2t[n * F_HID + k] = f2bf(v);
        }
    }
}

// ---------------- GEMM1 (MFMA bf16): x[N,256]f32 @ W1 -> h[N,128] fp8-e4m3 ----------------
__global__ __launch_bounds__(256) void k_gemm1(const float* __restrict__ A,
                                               const unsigned short* __restrict__ Wt,
                                               unsigned char* __restrict__ C) {
    __shared__ unsigned short As[128][40];
    __shared__ unsigned short Ws[128][40];
    int t = threadIdx.x;
    int wave = t >> 6, lane = t & 63;
    int quad = lane >> 4, l16 = lane & 15;
    int row0 = blockIdx.x * 128;
    floatx4 acc[2][8];
    #pragma unroll
    for (int i = 0; i < 2; ++i)
        #pragma unroll
        for (int j = 0; j < 8; ++j)
            #pragma unroll
            for (int r = 0; r < 4; ++r) acc[i][j][r] = 0.0f;

    for (int k0 = 0; k0 < F_IN; k0 += 32) {
        #pragma unroll
        for (int i = 0; i < 4; ++i) {
            int idx = t + i * 256;
            int r = idx >> 3, c = idx & 7;
            int gr = row0 + r; if (gr > N_NODES - 1) gr = N_NODES - 1;
            float4 va = *(const float4*)(A + (size_t)gr * F_IN + k0 + c * 4);
            ushort4 u;
            u.x = f2bf(va.x); u.y = f2bf(va.y); u.z = f2bf(va.z); u.w = f2bf(va.w);
            *(ushort4*)(&As[r][c * 4]) = u;
        }
        #pragma unroll
        for (int i = 0; i < 2; ++i) {
            int idx = t + i * 256;
            int n = idx >> 2, c = idx & 3;
            ushort4 w0 = *(const ushort4*)(Wt + (size_t)n * F_IN + k0 + c * 8);
            ushort4 w1 = *(const ushort4*)(Wt + (size_t)n * F_IN + k0 + c * 8 + 4);
            *(ushort4*)(&Ws[n][c * 8]) = w0;
            *(ushort4*)(&Ws[n][c * 8 + 4]) = w1;
        }
        __syncthreads();
        short8 af[2];
        #pragma unroll
        for (int rt = 0; rt < 2; ++rt)
            af[rt] = *(const short8*)(&As[wave * 32 + rt * 16 + l16][quad * 8]);
        #pragma unroll
        for (int ct = 0; ct < 8; ++ct) {
            short8 bf = *(const short8*)(&Ws[ct * 16 + l16][quad * 8]);
            acc[0][ct] = __builtin_amdgcn_mfma_f32_16x16x32_bf16(af[0], bf, acc[0][ct], 0, 0, 0);
            acc[1][ct] = __builtin_amdgcn_mfma_f32_16x16x32_bf16(af[1], bf, acc[1][ct], 0, 0, 0);
        }
        __syncthreads();
    }
    #pragma unroll
    for (int rt = 0; rt < 2; ++rt) {
        #pragma unroll
        for (int ct = 0; ct < 8; ++ct) {
            #pragma unroll
            for (int r = 0; r < 4; ++r) {
                int row = row0 + wave * 32 + rt * 16 + quad * 4 + r;
                if (row < N_NODES)
                    C[(size_t)row * F_HID + ct * 16 + l16] = f2fp8(acc[rt][ct][r]);
            }
        }
    }
}

// ---------------- agg1: h (fp8) gather, 4 quarter-waves x 4 edges in flight ----------------
#define ACCF8(u2, wgt) { \
    floatx2 p0 = __builtin_amdgcn_cvt_pk_f32_fp8(u2.x, false); \
    floatx2 p1 = __builtin_amdgcn_cvt_pk_f32_fp8(u2.x, true); \
    floatx2 p2 = __builtin_amdgcn_cvt_pk_f32_fp8(u2.y, false); \
    floatx2 p3 = __builtin_amdgcn_cvt_pk_f32_fp8(u2.y, true); \
    a[0] += wgt * p0.x; a[1] += wgt * p0.y; a[2] += wgt * p1.x; a[3] += wgt * p1.y; \
    a[4] += wgt * p2.x; a[5] += wgt * p2.y; a[6] += wgt * p3.x; a[7] += wgt * p3.y; }

__global__ __launch_bounds__(256) void k_agg1(const unsigned char* __restrict__ h_,
                                              const int* __restrict__ off,
                                              const int2* __restrict__ edges,
                                              const float* __restrict__ dinv,
                                              const float* __restrict__ b1,
                                              unsigned short* __restrict__ h1_) {
    const uint2* h = (const uint2*)h_;   // row = 16 uint2 (128 fp8)
    uint4* h1 = (uint4*)h1_;
    int node = blockIdx.x * 4 + (threadIdx.x >> 6);
    int lane = threadIdx.x & 63;
    int q = lane >> 4, l16 = lane & 15;
    if (node >= N_NODES) return;
    int s0 = off[node], s1 = off[node + 1];
    int nE = s1 - s0;
    float dn = dinv[node];
    float a[8] = {};
    if (q == 0) {
        uint2 sv = h[(size_t)node * 16 + l16];
        ACCF8(sv, dn);
    }
    int end4 = s0 + (nE & ~3);
    int e = s0 + q;
    for (; e + 12 < end4; e += 16) {
        int2 r0 = edges[e], r1 = edges[e + 4], r2 = edges[e + 8], r3 = edges[e + 12];
        uint2 v0 = h[(size_t)r0.x * 16 + l16];
        uint2 v1 = h[(size_t)r1.x * 16 + l16];
        uint2 v2 = h[(size_t)r2.x * 16 + l16];
        uint2 v3 = h[(size_t)r3.x * 16 + l16];
        ACCF8(v0, __int_as_float(r0.y));
        ACCF8(v1, __int_as_float(r1.y));
        ACCF8(v2, __int_as_float(r2.y));
        ACCF8(v3, __int_as_float(r3.y));
    }
    for (; e < end4; e += 4) {
        int2 r0 = edges[e];
        uint2 v0 = h[(size_t)r0.x * 16 + l16];
        ACCF8(v0, __int_as_float(r0.y));
    }
    if (q < (nE & 3)) {
        int2 r0 = edges[end4 + q];
        uint2 v0 = h[(size_t)r0.x * 16 + l16];
        ACCF8(v0, __int_as_float(r0.y));
    }
    #pragma unroll
    for (int i = 0; i < 8; ++i) {
        a[i] += __shfl_xor(a[i], 16);
        a[i] += __shfl_xor(a[i], 32);
    }
    if (q == 0) {
        float4 bb0 = ((const float4*)b1)[l16 * 2];
        float4 bb1 = ((const float4*)b1)[l16 * 2 + 1];
        unsigned short c0 = f2bf(fmaxf(a[0] * dn + bb0.x, 0.0f));
        unsigned short c1 = f2bf(fmaxf(a[1] * dn + bb0.y, 0.0f));
        unsigned short c2 = f2bf(fmaxf(a[2] * dn + bb0.z, 0.0f));
        unsigned short c3 = f2bf(fmaxf(a[3] * dn + bb0.w, 0.0f));
        unsigned short c4 = f2bf(fmaxf(a[4] * dn + bb1.x, 0.0f));
        unsigned short c5 = f2bf(fmaxf(a[5] * dn + bb1.y, 0.0f));
        unsigned short c6 = f2bf(fmaxf(a[6] * dn + bb1.z, 0.0f));
        unsigned short c7 = f2bf(fmaxf(a[7] * dn + bb1.w, 0.0f));
        uint4 r;
        r.x = (unsigned int)c0 | ((unsigned int)c1 << 16);
        r.y = (unsigned int)c2 | ((unsigned int)c3 << 16);
        r.z = (unsigned int)c4 | ((unsigned int)c5 << 16);
        r.w = (unsigned int)c6 | ((unsigned int)c7 << 16);
        h1[(size_t)node * 16 + l16] = r;
    }
}

// ---------------- GEMM2 (MFMA bf16): h1[N,128]bf16 @ W2 -> h2[N,64] fp8-e4m3 ----------------
__global__ __launch_bounds__(256) void k_gemm2(const unsigned short* __restrict__ A,
                                               const unsigned short* __restrict__ Wt,
                                               unsigned char* __restrict__ C) {
    __shared__ unsigned short As[128][136];
    __shared__ unsigned short Ws[64][136];
    int t = threadIdx.x;
    int wave = t >> 6, lane = t & 63;
    int quad = lane >> 4, l16 = lane & 15;
    int row0 = blockIdx.x * 128;
    floatx4 acc[2][4];
    #pragma unroll
    for (int i = 0; i < 2; ++i)
        #pragma unroll
        for (int j = 0; j < 4; ++j)
            #pragma unroll
            for (int r = 0; r < 4; ++r) acc[i][j][r] = 0.0f;

    #pragma unroll
    for (int i = 0; i < 8; ++i) {
        int idx = t + i * 256;
        int r = idx >> 4, c = idx & 15;
        int gr = row0 + r; if (gr > N_NODES - 1) gr = N_NODES - 1;
        ushort4 w0 = *(const ushort4*)(A + (size_t)gr * F_HID + c * 8);
        ushort4 w1 = *(const ushort4*)(A + (size_t)gr * F_HID + c * 8 + 4);
        *(ushort4*)(&As[r][c * 8]) = w0;
        *(ushort4*)(&As[r][c * 8 + 4]) = w1;
    }
    #pragma unroll
    for (int i = 0; i < 4; ++i) {
        int idx = t + i * 256;
        int n = idx >> 4, c = idx & 15;
        ushort4 w0 = *(const ushort4*)(Wt + (size_t)n * F_HID + c * 8);
        ushort4 w1 = *(const ushort4*)(Wt + (size_t)n * F_HID + c * 8 + 4);
        *(ushort4*)(&Ws[n][c * 8]) = w0;
        *(ushort4*)(&Ws[n][c * 8 + 4]) = w1;
    }
    __syncthreads();
    #pragma unroll
    for (int ks = 0; ks < 4; ++ks) {
        int k0 = ks * 32;
        short8 af[2];
        #pragma unroll
        for (int rt = 0; rt < 2; ++rt)
            af[rt] = *(const short8*)(&As[wave * 32 + rt * 16 + l16][k0 + quad * 8]);
        #pragma unroll
        for (int ct = 0; ct < 4; ++ct) {
            short8 bf = *(const short8*)(&Ws[ct * 16 + l16][k0 + quad * 8]);
            acc[0][ct] = __builtin_amdgcn_mfma_f32_16x16x32_bf16(af[0], bf, acc[0][ct], 0, 0, 0);
            acc[1][ct] = __builtin_amdgcn_mfma_f32_16x16x32_bf16(af[1], bf, acc[1][ct], 0, 0, 0);
        }
    }
    #pragma unroll
    for (int rt = 0; rt < 2; ++rt) {
        #pragma unroll
        for (int ct = 0; ct < 4; ++ct) {
            #pragma unroll
            for (int r = 0; r < 4; ++r) {
                int row = row0 + wave * 32 + rt * 16 + quad * 4 + r;
                if (row < N_NODES)
                    C[(size_t)row * F_OUT_P + ct * 16 + l16] = f2fp8(acc[rt][ct][r]);
            }
        }
    }
}

// ---------------- agg2 + bias + log_softmax: h2 fp8, 8-lane groups, 8 edges in flight ----------------
// group g = lane>>3 handles edges e = s0+g, step 8; lane loads uint2 (8 fp8 cols).
__global__ __launch_bounds__(256) void k_agg2(const unsigned char* __restrict__ h2_,
                                              const int* __restrict__ off,
                                              const int2* __restrict__ edges,
                                              const float* __restrict__ dinv,
                                              const float* __restrict__ b2,
                                              float* __restrict__ out) {
    const uint2* h2 = (const uint2*)h2_;  // row = 8 uint2 (64 fp8)
    int node = blockIdx.x * 4 + (threadIdx.x >> 6);
    int lane = threadIdx.x & 63;
    int g = lane >> 3, l8 = lane & 7;
    if (node >= N_NODES) return;
    int s0 = off[node], s1 = off[node + 1];
    int nE = s1 - s0;
    float dn = dinv[node];
    float a[8] = {};
    if (g == 0) {
        uint2 sv = h2[(size_t)node * 8 + l8];
        ACCF8(sv, dn);
    }
    int end8 = s0 + (nE & ~7);
    int e = s0 + g;
    for (; e + 8 < end8; e += 16) {
        int2 r0 = edges[e], r1 = edges[e + 8];
        uint2 v0 = h2[(size_t)r0.x * 8 + l8];
        uint2 v1 = h2[(size_t)r1.x * 8 + l8];
        ACCF8(v0, __int_as_float(r0.y));
        ACCF8(v1, __int_as_float(r1.y));
    }
    for (; e < end8; e += 8) {
        int2 r0 = edges[e];
        uint2 v0 = h2[(size_t)r0.x * 8 + l8];
        ACCF8(v0, __int_as_float(r0.y));
    }
    if (g < (nE & 7)) {
        int2 r0 = edges[end8 + g];
        uint2 v0 = h2[(size_t)r0.x * 8 + l8];
        ACCF8(v0, __int_as_float(r0.y));
    }
    #pragma unroll
    for (int i = 0; i < 8; ++i) {
        a[i] += __shfl_xor(a[i], 8);
        a[i] += __shfl_xor(a[i], 16);
        a[i] += __shfl_xor(a[i], 32);
    }
    // lanes with same l8 hold identical sums for cols 8*l8 .. 8*l8+7
    int c0 = l8 * 8;
    float v[8];
    #pragma unroll
    for (int j = 0; j < 8; ++j)
        v[j] = (c0 + j < F_OUT) ? (a[j] * dn + b2[c0 + j]) : -3.4e38f;
    float m = v[0];
    #pragma unroll
    for (int j = 1; j < 8; ++j) m = fmaxf(m, v[j]);
    #pragma unroll
    for (int o = 4; o > 0; o >>= 1) m = fmaxf(m, __shfl_xor(m, o));
    float ex = 0.0f;
    #pragma unroll
    for (int j = 0; j < 8; ++j)
        if (c0 + j < F_OUT) ex += __expf(v[j] - m);
    #pragma unroll
    for (int o = 4; o > 0; o >>= 1) ex += __shfl_xor(ex, o);
    float ls = __logf(ex);
    if (g == 0 && c0 < F_OUT) {
        float4 o0 = make_float4(v[0] - m - ls, v[1] - m - ls, v[2] - m - ls, v[3] - m - ls);
        float4 o1 = make_float4(v[4] - m - ls, v[5] - m - ls, v[6] - m - ls, v[7] - m - ls);
        *(float4*)(out + (size_t)node * F_OUT + c0) = o0;
        *(float4*)(out + (size_t)node * F_OUT + c0 + 4) = o1;
    }
}

// ---------------- launch ----------------
static inline char* alignup(char* p) {
    return (char*)(((uintptr_t)p + 255) & ~(uintptr_t)255);
}

extern "C" void kernel_launch(void* const* d_in, const int* in_sizes, int n_in,
                              void* d_out, int out_size, void* d_ws, size_t ws_size,
                              hipStream_t stream) {
    const float* x  = (const float*)d_in[0];
    const int*   ei = (const int*)d_in[1];
    const float* W1 = (const float*)d_in[2];
    const float* b1 = (const float*)d_in[3];
    const float* W2 = (const float*)d_in[4];
    const float* b2 = (const float*)d_in[5];
    float* out = (float*)d_out;

    char* w = (char*)d_ws;
    int* gtot  = (int*)w;             w = alignup(w + (size_t)NBKT * 4);
    int* boff  = (int*)w;             w = alignup(w + (size_t)(NBKT + 1) * 4);
    int* bcur  = (int*)w;             w = alignup(w + (size_t)NBKT * 4);
    int* off   = (int*)w;             w = alignup(w + (size_t)(N_NODES + 1) * 4);
    float* dinv = (float*)w;          w = alignup(w + (size_t)N_NODES * 4);
    int2* edges = (int2*)w;           w = alignup(w + (size_t)N_EDGES * 8);
    unsigned short* W1t = (unsigned short*)w;  w = alignup(w + (size_t)F_HID * F_IN * 2);
    unsigned short* W2t = (unsigned short*)w;  w = alignup(w + (size_t)F_OUT_P * F_HID * 2);
    unsigned char* h    = (unsigned char*)w;   w = alignup(w + (size_t)N_NODES * F_HID);      // fp8
    unsigned short* h1  = (unsigned short*)w;  w = alignup(w + (size_t)N_NODES * F_HID * 2);
    unsigned char* h2   = (unsigned char*)w;   w = alignup(w + (size_t)N_NODES * F_OUT_P);    // fp8
    // lifetime-disjoint aliases (binned dead before gemm1 writes h; ssrc dead before agg1 writes h1)
    unsigned int* binned = (unsigned int*)h;   // 6.4 MB < 12.8 MB
    int* ssrc            = (int*)h1;           // 6.4 MB < 25.6 MB

    const int* srcp = ei;
    const int* dstp = ei + N_EDGES;

    hipMemsetAsync(gtot, 0, (size_t)NBKT * 4, stream);
    k_hist<<<P1_NBLK, 256, 0, stream>>>(dstp, gtot);
    k_bktscan<<<1, 256, 0, stream>>>(gtot, boff, bcur);
    k_bin<<<P1_NBLK, 256, 0, stream>>>(srcp, dstp, bcur, binned);
    k_place<<<NBKT, 256, 0, stream>>>(binned, boff, off, dinv, ssrc);
    k_mkrec<<<(N_EDGES / 4 + 255) / 256, 256, 0, stream>>>(ssrc, dinv, edges);

    k_convW<<<(F_IN * F_HID + F_OUT_P * F_HID + 255) / 256, 256, 0, stream>>>(W1, W2, W1t, W2t);

    k_gemm1<<<(N_NODES + 127) / 128, 256, 0, stream>>>(x, W1t, h);
    k_agg1<<<(N_NODES + 3) / 4, 256, 0, stream>>>(h, off, edges, dinv, b1, h1);
    k_gemm2<<<(N_NODES + 127) / 128, 256, 0, stream>>>(h1, W2t, h2);
    k_agg2<<<(N_NODES + 3) / 4, 256, 0, stream>>>(h2, off, edges, dinv, b2, out);
}